// Round 3
// baseline (752.035 us; speedup 1.0000x reference)
//
#include <hip/hip_runtime.h>
#include <hip/hip_bf16.h>

#define T_TOK 4096
#define HDIM 1024
#define IDIM 4096
#define NEXP 8
#define MAXRB 72
#define G2_RBG 16   // per-expert row-block slots in gemm2 grid (covers 2048 rows/expert)

typedef __bf16 bf16x8 __attribute__((ext_vector_type(8)));
typedef float f32x4 __attribute__((ext_vector_type(4)));
typedef unsigned short us8 __attribute__((ext_vector_type(8)));

__device__ __forceinline__ unsigned short f2bf(float f) {
    union { float f; unsigned int u; } v; v.f = f;
    unsigned int u = v.u;
    unsigned int r = u + 0x7fffu + ((u >> 16) & 1u);
    return (unsigned short)(r >> 16);
}
__device__ __forceinline__ float bf2f(unsigned short b) {
    union { unsigned int u; float f; } v; v.u = ((unsigned int)b) << 16;
    return v.f;
}

// async 16B/lane global->LDS: wave-uniform lds base, lane l lands at base + l*16
__device__ __forceinline__ void gll16(const unsigned short* g, unsigned short* lds) {
    __builtin_amdgcn_global_load_lds(
        (const __attribute__((address_space(1))) unsigned int*)g,
        (__attribute__((address_space(3))) unsigned int*)lds, 16, 0, 0);
}

// Abramowitz-Stegun 7.1.26 erf (|err| <= 1.5e-7), exact-erf GELU
__device__ __forceinline__ float gelu_f(float v) {
    float x = v * 0.70710678118654752f;
    float ax = fabsf(x);
    float t = __builtin_amdgcn_rcpf(1.0f + 0.3275911f * ax);
    float p = t * (0.254829592f + t * (-0.284496736f + t * (1.421413741f
              + t * (-1.453152027f + t * 1.061405429f))));
    float ex = __expf(-x * x);
    float er = 1.0f - p * ex;
    er = copysignf(er, x);
    return 0.5f * v * (1.0f + er);
}

// ---------------- transpose+convert: src [E][R][C] f32 -> dst [E][C][R] bf16 ----------------
__global__ __launch_bounds__(256) void k_cvt_t(const float* __restrict__ src,
                                               unsigned short* __restrict__ dst,
                                               int R, int C) {
    __shared__ unsigned short tl[64][72];
    const int e = blockIdx.z;
    const int c0 = blockIdx.x * 64, r0 = blockIdx.y * 64;
    const int tid = threadIdx.x;
    #pragma unroll
    for (int it = 0; it < 4; it++) {
        int idx = it * 256 + tid;
        int rl = idx >> 4, cl = (idx & 15) * 4;
        float4 v = *(const float4*)(src + ((size_t)e * R + r0 + rl) * C + c0 + cl);
        tl[cl + 0][rl] = f2bf(v.x);
        tl[cl + 1][rl] = f2bf(v.y);
        tl[cl + 2][rl] = f2bf(v.z);
        tl[cl + 3][rl] = f2bf(v.w);
    }
    __syncthreads();
    #pragma unroll
    for (int it = 0; it < 2; it++) {
        int idx = it * 256 + tid;
        int cl = idx >> 3, ch = idx & 7;
        us8 v;
        __builtin_memcpy(&v, &tl[cl][ch * 8], 16);
        *(us8*)(dst + ((size_t)e * C + c0 + cl) * R + r0 + ch * 8) = v;
    }
}

// ---------------- LN stats + router top-2 + routing lists ----------------
__global__ __launch_bounds__(256) void k_ln_router(
    const float* __restrict__ x, const float* __restrict__ rlw, const float* __restrict__ rlb,
    const float* __restrict__ rw, const float* __restrict__ rb,
    unsigned short* __restrict__ xhat, int* __restrict__ counts,
    int* __restrict__ ltok, float* __restrict__ lwt)
{
    const int t = blockIdx.x, tid = threadIdx.x;
    const float4 v = *(const float4*)(x + (size_t)t * HDIM + tid * 4);
    float s  = v.x + v.y + v.z + v.w;
    float sq = v.x*v.x + v.y*v.y + v.z*v.z + v.w*v.w;
    for (int o = 32; o > 0; o >>= 1) { s += __shfl_xor(s, o); sq += __shfl_xor(sq, o); }
    __shared__ float red[8];
    __shared__ float stats[2];
    const int wid = tid >> 6, lane = tid & 63;
    if (lane == 0) { red[wid] = s; red[4 + wid] = sq; }
    __syncthreads();
    if (tid == 0) {
        float S = red[0] + red[1] + red[2] + red[3];
        float Q = red[4] + red[5] + red[6] + red[7];
        float mu = S / (float)HDIM;
        float var = Q / (float)HDIM - mu * mu;
        stats[0] = mu; stats[1] = rsqrtf(var + 1e-5f);
    }
    __syncthreads();
    const float mu = stats[0], rstd = stats[1];
    float xh[4];
    xh[0] = (v.x - mu) * rstd; xh[1] = (v.y - mu) * rstd;
    xh[2] = (v.z - mu) * rstd; xh[3] = (v.w - mu) * rstd;
    ushort4 o4;
    o4.x = f2bf(xh[0]); o4.y = f2bf(xh[1]); o4.z = f2bf(xh[2]); o4.w = f2bf(xh[3]);
    *(ushort4*)(xhat + (size_t)t * HDIM + tid * 4) = o4;

    float p[8];
    #pragma unroll
    for (int e = 0; e < 8; e++) p[e] = 0.f;
    const float4 w4 = *(const float4*)(rlw + tid * 4);
    const float4 b4 = *(const float4*)(rlb + tid * 4);
    const float wl[4] = { w4.x, w4.y, w4.z, w4.w };
    const float bl[4] = { b4.x, b4.y, b4.z, b4.w };
    #pragma unroll
    for (int j = 0; j < 4; j++) {
        float rl = xh[j] * wl[j] + bl[j];
        const float* wr = rw + (size_t)(tid * 4 + j) * 8;
        float4 wa = *(const float4*)(wr);
        float4 wb = *(const float4*)(wr + 4);
        p[0] += rl * wa.x; p[1] += rl * wa.y; p[2] += rl * wa.z; p[3] += rl * wa.w;
        p[4] += rl * wb.x; p[5] += rl * wb.y; p[6] += rl * wb.z; p[7] += rl * wb.w;
    }
    #pragma unroll
    for (int e = 0; e < 8; e++)
        for (int o = 32; o > 0; o >>= 1) p[e] += __shfl_xor(p[e], o);
    __shared__ float pw[4][8];
    if (lane == 0) {
        #pragma unroll
        for (int e = 0; e < 8; e++) pw[wid][e] = p[e];
    }
    __syncthreads();
    if (tid == 0) {
        float lg[8];
        #pragma unroll
        for (int e = 0; e < 8; e++)
            lg[e] = pw[0][e] + pw[1][e] + pw[2][e] + pw[3][e] + rb[e];
        int i0 = 0;
        #pragma unroll
        for (int e = 1; e < 8; e++) if (lg[e] > lg[i0]) i0 = e;
        int i1 = (i0 == 0) ? 1 : 0;
        #pragma unroll
        for (int e = 0; e < 8; e++) if (e != i0 && lg[e] > lg[i1]) i1 = e;
        float e1 = expf(lg[i1] - lg[i0]);
        float w0 = 1.f / (1.f + e1);
        float w1 = 1.f - w0;
        int p0 = atomicAdd(&counts[i0], 1);
        ltok[i0 * T_TOK + p0] = t * 2 + 0; lwt[i0 * T_TOK + p0] = w0;
        int p1 = atomicAdd(&counts[i1], 1);
        ltok[i1 * T_TOK + p1] = t * 2 + 1; lwt[i1 * T_TOK + p1] = w1;
    }
}

// ---------------- prefix sum + row-block schedule table ----------------
__global__ void k_sched(const int* __restrict__ counts, int* __restrict__ offs,
                        int* __restrict__ rb_e, int* __restrict__ rb_rt) {
    if (threadIdx.x == 0 && blockIdx.x == 0) {
        int a = 0;
        for (int e = 0; e < NEXP; e++) { offs[e] = a; a += counts[e]; }
        offs[NEXP] = a;
        int i = 0;
        for (int e = 0; e < NEXP; e++) {
            int nrb = (counts[e] + 127) >> 7;
            for (int rt = 0; rt < nrb; rt++) { rb_e[i] = e; rb_rt[i] = rt; i++; }
        }
        for (; i < MAXRB; i++) { rb_e[i] = -1; rb_rt[i] = 0; }
    }
}

// ---------------- build packed, expert-LN-affined A (bf16) ----------------
__global__ __launch_bounds__(256) void k_ag_build(
    const unsigned short* __restrict__ xhat, const float* __restrict__ elw, const float* __restrict__ elb,
    const int* __restrict__ counts, const int* __restrict__ offs, const int* __restrict__ ltok,
    unsigned short* __restrict__ ag)
{
    const int e = blockIdx.z, rt = blockIdx.x, cc = blockIdx.y;
    const int ne = counts[e];
    if (rt * 128 >= ne) return;
    const int off = offs[e];
    const int tid = threadIdx.x;
    const int row = rt * 128 + (tid >> 1);
    if (row >= ne) return;
    const int tok = ltok[e * T_TOK + row] >> 1;
    const int cb = cc * 256 + (tid & 1) * 128;
    const unsigned short* src = xhat + (size_t)tok * HDIM + cb;
    unsigned short* dst = ag + (size_t)(off + row) * HDIM + cb;
    const float* wv = elw + (size_t)e * HDIM + cb;
    const float* bv = elb + (size_t)e * HDIM + cb;
    #pragma unroll
    for (int j = 0; j < 128; j += 8) {
        us8 xv = *(const us8*)(src + j);
        us8 o;
        #pragma unroll
        for (int q = 0; q < 8; q++)
            o[q] = f2bf(bf2f(xv[q]) * wv[j + q] + bv[j + q]);
        *(us8*)(dst + j) = o;
    }
}

// ======================= pipelined grouped GEMMs (BK=32) ===============
// LDS tile 128x32 bf16, row = 64 B. Swizzle: stored_chunk = global_chunk ^ ((row>>1)&3)
//   -> both DMA writes and ds_read_b128 are conflict-free per 8-lane phase.

// 128x128 tile, 4 waves as 2x2 of 64x64, acc 4x4
#define GEMM_COMPUTE32(ASb, BSb)                                                \
    {                                                                           \
        bf16x8 af[4], bfr[4];                                                   \
        const int sw_ = (quad ^ ((fr >> 1) & 3)) * 8;                           \
        _Pragma("unroll")                                                       \
        for (int i_ = 0; i_ < 4; i_++)                                          \
            __builtin_memcpy(&af[i_], (ASb) + (wm + i_ * 16 + fr) * 32 + sw_, 16);\
        _Pragma("unroll")                                                       \
        for (int j_ = 0; j_ < 4; j_++)                                          \
            __builtin_memcpy(&bfr[j_], (BSb) + (wn + j_ * 16 + fr) * 32 + sw_, 16);\
        _Pragma("unroll")                                                       \
        for (int i_ = 0; i_ < 4; i_++)                                          \
            _Pragma("unroll")                                                   \
            for (int j_ = 0; j_ < 4; j_++)                                      \
                acc[i_][j_] = __builtin_amdgcn_mfma_f32_16x16x32_bf16(          \
                    af[i_], bfr[j_], acc[i_][j_], 0, 0, 0);                     \
    }

// ---------------- GEMM1: Ag @ w1bf^T -> +b1 -> gelu -> hbuf (bf16) ----------------
// grid: x = ct (XCD-affine for B stripes), y = row-block schedule; depth-2 dbuf,
// vmcnt(4) counted wait (operands mostly L2/L3-resident; 5 blocks/CU).
__global__ __launch_bounds__(256, 5) void k_gemm1(
    const unsigned short* __restrict__ ag, const unsigned short* __restrict__ wbf,
    const float* __restrict__ b1,
    const int* __restrict__ counts, const int* __restrict__ offs,
    const int* __restrict__ rb_e, const int* __restrict__ rb_rt,
    unsigned short* __restrict__ hbuf)
{
    const int e = rb_e[blockIdx.y];
    if (e < 0) return;
    const int rt = rb_rt[blockIdx.y], ct = blockIdx.x;
    const int ne = counts[e], off = offs[e];
    __shared__ unsigned short As[2 * 128 * 32];
    __shared__ unsigned short Bs[2 * 128 * 32];
    const int tid = threadIdx.x, wid = tid >> 6, lane = tid & 63;
    // staging lane map: row = 32*wid + 16*i_ + (lane>>2); fetch k-chunk = (lane&3)^((lane>>3)&3)
    const int srow = 32 * wid + (lane >> 2);
    const int kswz = ((lane & 3) ^ ((lane >> 3) & 3)) * 8;
    const unsigned short* gA = ag + (size_t)(off + rt * 128 + srow) * HDIM + kswz;
    const unsigned short* gB = wbf + (size_t)e * IDIM * HDIM
                             + (size_t)(ct * 128 + srow) * HDIM + kswz;
    const int wso = wid * 1024;

    f32x4 acc[4][4];
    #pragma unroll
    for (int i = 0; i < 4; i++)
        #pragma unroll
        for (int j = 0; j < 4; j++) acc[i][j] = (f32x4){0.f, 0.f, 0.f, 0.f};

    const int wm = (wid & 1) * 64, wn = (wid >> 1) * 64;
    const int fr = lane & 15, quad = lane >> 4;

    const int NK = HDIM / 32;  // 32
    {   // prologue -> buf 0
        unsigned short* dA = As + wso;
        unsigned short* dB = Bs + wso;
        gll16(gA, dA); gll16(gA + (size_t)16 * HDIM, dA + 512);
        gll16(gB, dB); gll16(gB + (size_t)16 * HDIM, dB + 512);
    }
    #pragma unroll 1
    for (int kt = 0; kt < NK - 1; ++kt) {
        const int b = kt & 1;
        unsigned short* dA = As + (1 - b) * 4096 + wso;
        unsigned short* dB = Bs + (1 - b) * 4096 + wso;
        const size_t ko = (size_t)(kt + 1) * 32;
        gll16(gA + ko, dA); gll16(gA + (size_t)16 * HDIM + ko, dA + 512);
        gll16(gB + ko, dB); gll16(gB + (size_t)16 * HDIM + ko, dB + 512);
        asm volatile("s_waitcnt vmcnt(4)" ::: "memory");
        asm volatile("s_barrier" ::: "memory");
        GEMM_COMPUTE32(As + b * 4096, Bs + b * 4096);
        asm volatile("s_barrier" ::: "memory");
    }
    asm volatile("s_waitcnt vmcnt(0)" ::: "memory");
    asm volatile("s_barrier" ::: "memory");
    GEMM_COMPUTE32(As + ((NK - 1) & 1) * 4096, Bs + ((NK - 1) & 1) * 4096);

    // epilogue: + b1, gelu(erf), -> bf16 h
    float bias[4];
    #pragma unroll
    for (int j = 0; j < 4; j++) bias[j] = b1[e * IDIM + ct * 128 + wn + j * 16 + fr];
    #pragma unroll
    for (int i = 0; i < 4; i++) {
        #pragma unroll
        for (int rg = 0; rg < 4; rg++) {
            const int r = rt * 128 + wm + i * 16 + quad * 4 + rg;
            if (r < ne) {
                unsigned short* hrow = hbuf + (size_t)(off + r) * IDIM + ct * 128 + wn + fr;
                #pragma unroll
                for (int j = 0; j < 4; j++)
                    hrow[j * 16] = f2bf(gelu_f(acc[i][j][rg] + bias[j]));
            }
        }
    }
}

// ---------------- GEMM2: hbuf @ w2bf -> +b2 -> *wt -> eo[t,slot,:] ----------------
// 128x128 tile. Grid-limited to 2 blocks/CU (N=1024 -> 8 cts), so:
//  (a) expert==XCD clustering: bid&7 = e -> each XCD runs ONE expert; its 8MB B
//      panel and 8MB A rows are L2-local, shared by its ~64 concurrent blocks.
//  (b) depth-4 LDS pipeline (64KB): stage buf kt+3, steady s_waitcnt vmcnt(12)
//      -> each load has ~3 K-steps to complete (HBM latency tolerant at 2 blk/CU).
__global__ __launch_bounds__(256, 2) void k_gemm2(
    const unsigned short* __restrict__ hbuf, const unsigned short* __restrict__ wbf,
    const float* __restrict__ b2,
    const int* __restrict__ counts, const int* __restrict__ offs,
    const int* __restrict__ ltok, const float* __restrict__ lwt,
    float* __restrict__ eo)
{
    const int bid = blockIdx.x;
    const int e = bid & 7;            // expert == XCD (bid%8 dispatch heuristic)
    const int slot = bid >> 3;
    const int ct = slot & 7;          // 8 column tiles of N=1024
    const int rt = slot >> 3;         // row-block within expert, 0..G2_RBG-1
    const int ne = counts[e];
    if (rt * 128 >= ne) return;
    const int off = offs[e];
    __shared__ unsigned short As[4 * 128 * 32];   // 32 KB, 4 bufs
    __shared__ unsigned short Bs[4 * 128 * 32];   // 32 KB, 4 bufs
    const int tid = threadIdx.x, wid = tid >> 6, lane = tid & 63;
    const int srow = 32 * wid + (lane >> 2);
    const int kswz = ((lane & 3) ^ ((lane >> 3) & 3)) * 8;
    const unsigned short* gA = hbuf + (size_t)(off + rt * 128 + srow) * IDIM + kswz;
    const unsigned short* gB = wbf + (size_t)e * HDIM * IDIM
                             + (size_t)(ct * 128 + srow) * IDIM + kswz;
    const int wso = wid * 1024;

    f32x4 acc[4][4];
    #pragma unroll
    for (int i = 0; i < 4; i++)
        #pragma unroll
        for (int j = 0; j < 4; j++) acc[i][j] = (f32x4){0.f, 0.f, 0.f, 0.f};

    const int wm = (wid & 1) * 64, wn = (wid >> 1) * 64;
    const int fr = lane & 15, quad = lane >> 4;

    const int NK = IDIM / 32;  // 128
    {   // prologue -> bufs 0,1,2 (12 loads/wave in flight)
        #pragma unroll
        for (int pb = 0; pb < 3; pb++) {
            unsigned short* dA = As + pb * 4096 + wso;
            unsigned short* dB = Bs + pb * 4096 + wso;
            const size_t ko = (size_t)pb * 32;
            gll16(gA + ko, dA); gll16(gA + (size_t)16 * IDIM + ko, dA + 512);
            gll16(gB + ko, dB); gll16(gB + (size_t)16 * IDIM + ko, dB + 512);
        }
    }
    #pragma unroll 1
    for (int kt = 0; kt < NK - 3; ++kt) {
        const int b = kt & 3;
        unsigned short* dA = As + ((kt + 3) & 3) * 4096 + wso;
        unsigned short* dB = Bs + ((kt + 3) & 3) * 4096 + wso;
        const size_t ko = (size_t)(kt + 3) * 32;
        gll16(gA + ko, dA); gll16(gA + (size_t)16 * IDIM + ko, dA + 512);
        gll16(gB + ko, dB); gll16(gB + (size_t)16 * IDIM + ko, dB + 512);
        asm volatile("s_waitcnt vmcnt(12)" ::: "memory");
        asm volatile("s_barrier" ::: "memory");
        GEMM_COMPUTE32(As + b * 4096, Bs + b * 4096);
        asm volatile("s_barrier" ::: "memory");
    }
    // epilogue K-steps: NK-3 (vmcnt 8), NK-2 (vmcnt 4), NK-1 (vmcnt 0)
    asm volatile("s_waitcnt vmcnt(8)" ::: "memory");
    asm volatile("s_barrier" ::: "memory");
    GEMM_COMPUTE32(As + ((NK - 3) & 3) * 4096, Bs + ((NK - 3) & 3) * 4096);
    asm volatile("s_barrier" ::: "memory");
    asm volatile("s_waitcnt vmcnt(4)" ::: "memory");
    asm volatile("s_barrier" ::: "memory");
    GEMM_COMPUTE32(As + ((NK - 2) & 3) * 4096, Bs + ((NK - 2) & 3) * 4096);
    asm volatile("s_barrier" ::: "memory");
    asm volatile("s_waitcnt vmcnt(0)" ::: "memory");
    asm volatile("s_barrier" ::: "memory");
    GEMM_COMPUTE32(As + ((NK - 1) & 3) * 4096, Bs + ((NK - 1) & 3) * 4096);

    // epilogue: + b2, * routing weight, scatter fp32 to eo[token*2+slot]
    float bias[4];
    #pragma unroll
    for (int j = 0; j < 4; j++) bias[j] = b2[e * HDIM + ct * 128 + wn + j * 16 + fr];
    #pragma unroll
    for (int i = 0; i < 4; i++) {
        #pragma unroll
        for (int rg = 0; rg < 4; rg++) {
            const int r = rt * 128 + wm + i * 16 + quad * 4 + rg;
            if (r < ne) {
                const int d = ltok[e * T_TOK + r];
                const float w = lwt[e * T_TOK + r];
                float* erow = eo + (size_t)d * HDIM + ct * 128 + wn + fr;
                #pragma unroll
                for (int j = 0; j < 4; j++)
                    erow[j * 16] = (acc[i][j][rg] + bias[j]) * w;
            }
        }
    }
}

// ---------------- combine + final LN ----------------
__global__ __launch_bounds__(256) void k_final(
    const float* __restrict__ eo, const float* __restrict__ ow, const float* __restrict__ ob,
    float* __restrict__ out)
{
    const int t = blockIdx.x, tid = threadIdx.x;
    const float4 a = *(const float4*)(eo + (size_t)(t * 2 + 0) * HDIM + tid * 4);
    const float4 b = *(const float4*)(eo + (size_t)(t * 2 + 1) * HDIM + tid * 4);
    float c0 = a.x + b.x, c1 = a.y + b.y, c2 = a.z + b.z, c3 = a.w + b.w;
    float s = c0 + c1 + c2 + c3;
    float sq = c0*c0 + c1*c1 + c2*c2 + c3*c3;
    for (int o = 32; o > 0; o >>= 1) { s += __shfl_xor(s, o); sq += __shfl_xor(sq, o); }
    __shared__ float red[8];
    __shared__ float stats[2];
    const int wid = tid >> 6, lane = tid & 63;
    if (lane == 0) { red[wid] = s; red[4 + wid] = sq; }
    __syncthreads();
    if (tid == 0) {
        float S = red[0] + red[1] + red[2] + red[3];
        float Q = red[4] + red[5] + red[6] + red[7];
        float mu = S / (float)HDIM;
        float var = Q / (float)HDIM - mu * mu;
        stats[0] = mu; stats[1] = rsqrtf(var + 1e-5f);
    }
    __syncthreads();
    const float mu = stats[0], rstd = stats[1];
    const float4 w4 = *(const float4*)(ow + tid * 4);
    const float4 b4 = *(const float4*)(ob + tid * 4);
    float4 o;
    o.x = (c0 - mu) * rstd * w4.x + b4.x;
    o.y = (c1 - mu) * rstd * w4.y + b4.y;
    o.z = (c2 - mu) * rstd * w4.z + b4.z;
    o.w = (c3 - mu) * rstd * w4.w + b4.w;
    *(float4*)(out + (size_t)t * HDIM + tid * 4) = o;
}

extern "C" void kernel_launch(void* const* d_in, const int* in_sizes, int n_in,
                              void* d_out, int out_size, void* d_ws, size_t ws_size,
                              hipStream_t stream) {
    const float* x   = (const float*)d_in[0];
    const float* rlw = (const float*)d_in[1];
    const float* rlb = (const float*)d_in[2];
    const float* rw  = (const float*)d_in[3];
    const float* rb  = (const float*)d_in[4];
    const float* elw = (const float*)d_in[5];
    const float* elb = (const float*)d_in[6];
    const float* w1  = (const float*)d_in[7];
    const float* b1  = (const float*)d_in[8];
    const float* w2  = (const float*)d_in[9];
    const float* b2  = (const float*)d_in[10];
    const float* ow  = (const float*)d_in[11];
    const float* ob  = (const float*)d_in[12];
    float* out = (float*)d_out;

    const size_t MB = 1024 * 1024;
    char* ws = (char*)d_ws;
    const bool big = ws_size >= 242 * MB;
    // small (~160.3 MB): wbf1 [0,64) | hbuf/xhat [64,128) | ag+eo share [128,160) | tail
    //   (w2 converted into wbf1 AFTER gemm1 — 256 MB fp32 stream evicts hbuf from L3)
    // big (~241.3 MB):   wbf1 [0,64) | hbuf/xhat [64,128) | wbf2 [128,192) |
    //                    eo [192,224) | ag [224,240.3) | tail — w2 converted up-front.
    unsigned short* wbf1 = (unsigned short*)(ws);
    unsigned short* hbuf = (unsigned short*)(ws + 64 * MB);
    unsigned short* xhat = (unsigned short*)(ws + 64 * MB);
    unsigned short* wbf2 = big ? (unsigned short*)(ws + 128 * MB) : wbf1;
    float* eo            = big ? (float*)(ws + 192 * MB) : (float*)(ws + 128 * MB);
    unsigned short* ag   = big ? (unsigned short*)(ws + 224 * MB)
                               : (unsigned short*)(ws + 128 * MB);
    char* tail           = ws + (big ? 241 * MB : 160 * MB);
    int* ltok            = (int*)(tail);
    float* lwt           = (float*)(tail + 131072);
    int* counts          = (int*)(tail + 262144);
    int* offs            = (int*)(tail + 262144 + 64);
    int* rb_e            = (int*)(tail + 262144 + 128);
    int* rb_rt           = (int*)(tail + 262144 + 512);

    hipMemsetAsync(counts, 0, 8 * sizeof(int), stream);
    // w1 [E][H][I] -> wbf1 [E][I][H] bf16
    k_cvt_t<<<dim3(IDIM / 64, HDIM / 64, NEXP), dim3(256), 0, stream>>>(w1, wbf1, HDIM, IDIM);
    if (big)  // w2 [E][I][H] -> wbf2 [E][H][I] bf16, up-front (keeps hbuf L3-hot later)
        k_cvt_t<<<dim3(HDIM / 64, IDIM / 64, NEXP), dim3(256), 0, stream>>>(w2, wbf2, IDIM, HDIM);
    k_ln_router<<<dim3(T_TOK), dim3(256), 0, stream>>>(x, rlw, rlb, rw, rb, xhat, counts, ltok, lwt);
    k_sched<<<dim3(1), dim3(64), 0, stream>>>(counts, offs, rb_e, rb_rt);
    k_ag_build<<<dim3(32, 4, NEXP), dim3(256), 0, stream>>>(xhat, elw, elb, counts, offs, ltok, ag);
    // gemm1 grid: x = ct (XCD-affine), y = compacted row-block schedule
    k_gemm1<<<dim3(IDIM / 128, MAXRB), dim3(256), 0, stream>>>(
        ag, wbf1, b1, counts, offs, rb_e, rb_rt, hbuf);
    if (!big)
        k_cvt_t<<<dim3(HDIM / 64, IDIM / 64, NEXP), dim3(256), 0, stream>>>(w2, wbf2, IDIM, HDIM);
    // gemm2: 1D grid, expert==XCD clustering; 8 experts x 8 cts x G2_RBG rbs
    k_gemm2<<<dim3(8 * 8 * G2_RBG), dim3(256), 0, stream>>>(
        hbuf, wbf2, b2, counts, offs, ltok, lwt, eo);
    k_final<<<dim3(T_TOK), dim3(256), 0, stream>>>(eo, ow, ob, out);
}

// Round 4
// 704.445 us; speedup vs baseline: 1.0676x; 1.0676x over previous
//
#include <hip/hip_runtime.h>
#include <hip/hip_bf16.h>

#define T_TOK 4096
#define HDIM 1024
#define IDIM 4096
#define NEXP 8
#define MAXRB 72
#define G2_RBG 32   // per-expert row-block slots in gemm2 grid (covers 4096 rows/expert)

typedef __bf16 bf16x8 __attribute__((ext_vector_type(8)));
typedef float f32x4 __attribute__((ext_vector_type(4)));
typedef unsigned short us8 __attribute__((ext_vector_type(8)));

__device__ __forceinline__ unsigned short f2bf(float f) {
    union { float f; unsigned int u; } v; v.f = f;
    unsigned int u = v.u;
    unsigned int r = u + 0x7fffu + ((u >> 16) & 1u);
    return (unsigned short)(r >> 16);
}
__device__ __forceinline__ float bf2f(unsigned short b) {
    union { unsigned int u; float f; } v; v.u = ((unsigned int)b) << 16;
    return v.f;
}

// async 16B/lane global->LDS: wave-uniform lds base, lane l lands at base + l*16
__device__ __forceinline__ void gll16(const unsigned short* g, unsigned short* lds) {
    __builtin_amdgcn_global_load_lds(
        (const __attribute__((address_space(1))) unsigned int*)g,
        (__attribute__((address_space(3))) unsigned int*)lds, 16, 0, 0);
}

// Abramowitz-Stegun 7.1.26 erf (|err| <= 1.5e-7), exact-erf GELU
__device__ __forceinline__ float gelu_f(float v) {
    float x = v * 0.70710678118654752f;
    float ax = fabsf(x);
    float t = __builtin_amdgcn_rcpf(1.0f + 0.3275911f * ax);
    float p = t * (0.254829592f + t * (-0.284496736f + t * (1.421413741f
              + t * (-1.453152027f + t * 1.061405429f))));
    float ex = __expf(-x * x);
    float er = 1.0f - p * ex;
    er = copysignf(er, x);
    return 0.5f * v * (1.0f + er);
}

// ---------------- transpose+convert: src [E][R][C] f32 -> dst [E][C][R] bf16 ----------------
__global__ __launch_bounds__(256) void k_cvt_t(const float* __restrict__ src,
                                               unsigned short* __restrict__ dst,
                                               int R, int C) {
    __shared__ unsigned short tl[64][72];
    const int e = blockIdx.z;
    const int c0 = blockIdx.x * 64, r0 = blockIdx.y * 64;
    const int tid = threadIdx.x;
    #pragma unroll
    for (int it = 0; it < 4; it++) {
        int idx = it * 256 + tid;
        int rl = idx >> 4, cl = (idx & 15) * 4;
        float4 v = *(const float4*)(src + ((size_t)e * R + r0 + rl) * C + c0 + cl);
        tl[cl + 0][rl] = f2bf(v.x);
        tl[cl + 1][rl] = f2bf(v.y);
        tl[cl + 2][rl] = f2bf(v.z);
        tl[cl + 3][rl] = f2bf(v.w);
    }
    __syncthreads();
    #pragma unroll
    for (int it = 0; it < 2; it++) {
        int idx = it * 256 + tid;
        int cl = idx >> 3, ch = idx & 7;
        us8 v;
        __builtin_memcpy(&v, &tl[cl][ch * 8], 16);
        *(us8*)(dst + ((size_t)e * C + c0 + cl) * R + r0 + ch * 8) = v;
    }
}

// ---------------- LN stats + router top-2 + routing lists ----------------
__global__ __launch_bounds__(256) void k_ln_router(
    const float* __restrict__ x, const float* __restrict__ rlw, const float* __restrict__ rlb,
    const float* __restrict__ rw, const float* __restrict__ rb,
    unsigned short* __restrict__ xhat, int* __restrict__ counts,
    int* __restrict__ ltok, float* __restrict__ lwt)
{
    const int t = blockIdx.x, tid = threadIdx.x;
    const float4 v = *(const float4*)(x + (size_t)t * HDIM + tid * 4);
    float s  = v.x + v.y + v.z + v.w;
    float sq = v.x*v.x + v.y*v.y + v.z*v.z + v.w*v.w;
    for (int o = 32; o > 0; o >>= 1) { s += __shfl_xor(s, o); sq += __shfl_xor(sq, o); }
    __shared__ float red[8];
    __shared__ float stats[2];
    const int wid = tid >> 6, lane = tid & 63;
    if (lane == 0) { red[wid] = s; red[4 + wid] = sq; }
    __syncthreads();
    if (tid == 0) {
        float S = red[0] + red[1] + red[2] + red[3];
        float Q = red[4] + red[5] + red[6] + red[7];
        float mu = S / (float)HDIM;
        float var = Q / (float)HDIM - mu * mu;
        stats[0] = mu; stats[1] = rsqrtf(var + 1e-5f);
    }
    __syncthreads();
    const float mu = stats[0], rstd = stats[1];
    float xh[4];
    xh[0] = (v.x - mu) * rstd; xh[1] = (v.y - mu) * rstd;
    xh[2] = (v.z - mu) * rstd; xh[3] = (v.w - mu) * rstd;
    ushort4 o4;
    o4.x = f2bf(xh[0]); o4.y = f2bf(xh[1]); o4.z = f2bf(xh[2]); o4.w = f2bf(xh[3]);
    *(ushort4*)(xhat + (size_t)t * HDIM + tid * 4) = o4;

    float p[8];
    #pragma unroll
    for (int e = 0; e < 8; e++) p[e] = 0.f;
    const float4 w4 = *(const float4*)(rlw + tid * 4);
    const float4 b4 = *(const float4*)(rlb + tid * 4);
    const float wl[4] = { w4.x, w4.y, w4.z, w4.w };
    const float bl[4] = { b4.x, b4.y, b4.z, b4.w };
    #pragma unroll
    for (int j = 0; j < 4; j++) {
        float rl = xh[j] * wl[j] + bl[j];
        const float* wr = rw + (size_t)(tid * 4 + j) * 8;
        float4 wa = *(const float4*)(wr);
        float4 wb = *(const float4*)(wr + 4);
        p[0] += rl * wa.x; p[1] += rl * wa.y; p[2] += rl * wa.z; p[3] += rl * wa.w;
        p[4] += rl * wb.x; p[5] += rl * wb.y; p[6] += rl * wb.z; p[7] += rl * wb.w;
    }
    #pragma unroll
    for (int e = 0; e < 8; e++)
        for (int o = 32; o > 0; o >>= 1) p[e] += __shfl_xor(p[e], o);
    __shared__ float pw[4][8];
    if (lane == 0) {
        #pragma unroll
        for (int e = 0; e < 8; e++) pw[wid][e] = p[e];
    }
    __syncthreads();
    if (tid == 0) {
        float lg[8];
        #pragma unroll
        for (int e = 0; e < 8; e++)
            lg[e] = pw[0][e] + pw[1][e] + pw[2][e] + pw[3][e] + rb[e];
        int i0 = 0;
        #pragma unroll
        for (int e = 1; e < 8; e++) if (lg[e] > lg[i0]) i0 = e;
        int i1 = (i0 == 0) ? 1 : 0;
        #pragma unroll
        for (int e = 0; e < 8; e++) if (e != i0 && lg[e] > lg[i1]) i1 = e;
        float e1 = expf(lg[i1] - lg[i0]);
        float w0 = 1.f / (1.f + e1);
        float w1 = 1.f - w0;
        int p0 = atomicAdd(&counts[i0], 1);
        ltok[i0 * T_TOK + p0] = t * 2 + 0; lwt[i0 * T_TOK + p0] = w0;
        int p1 = atomicAdd(&counts[i1], 1);
        ltok[i1 * T_TOK + p1] = t * 2 + 1; lwt[i1 * T_TOK + p1] = w1;
    }
}

// ---------------- prefix sum + row-block schedule table ----------------
__global__ void k_sched(const int* __restrict__ counts, int* __restrict__ offs,
                        int* __restrict__ rb_e, int* __restrict__ rb_rt) {
    if (threadIdx.x == 0 && blockIdx.x == 0) {
        int a = 0;
        for (int e = 0; e < NEXP; e++) { offs[e] = a; a += counts[e]; }
        offs[NEXP] = a;
        int i = 0;
        for (int e = 0; e < NEXP; e++) {
            int nrb = (counts[e] + 127) >> 7;
            for (int rt = 0; rt < nrb; rt++) { rb_e[i] = e; rb_rt[i] = rt; i++; }
        }
        for (; i < MAXRB; i++) { rb_e[i] = -1; rb_rt[i] = 0; }
    }
}

// ---------------- build packed, expert-LN-affined A (bf16) ----------------
__global__ __launch_bounds__(256) void k_ag_build(
    const unsigned short* __restrict__ xhat, const float* __restrict__ elw, const float* __restrict__ elb,
    const int* __restrict__ counts, const int* __restrict__ offs, const int* __restrict__ ltok,
    unsigned short* __restrict__ ag)
{
    const int e = blockIdx.z, rt = blockIdx.x, cc = blockIdx.y;
    const int ne = counts[e];
    if (rt * 128 >= ne) return;
    const int off = offs[e];
    const int tid = threadIdx.x;
    const int row = rt * 128 + (tid >> 1);
    if (row >= ne) return;
    const int tok = ltok[e * T_TOK + row] >> 1;
    const int cb = cc * 256 + (tid & 1) * 128;
    const unsigned short* src = xhat + (size_t)tok * HDIM + cb;
    unsigned short* dst = ag + (size_t)(off + row) * HDIM + cb;
    const float* wv = elw + (size_t)e * HDIM + cb;
    const float* bv = elb + (size_t)e * HDIM + cb;
    #pragma unroll
    for (int j = 0; j < 128; j += 8) {
        us8 xv = *(const us8*)(src + j);
        us8 o;
        #pragma unroll
        for (int q = 0; q < 8; q++)
            o[q] = f2bf(bf2f(xv[q]) * wv[j + q] + bv[j + q]);
        *(us8*)(dst + j) = o;
    }
}

// ======================= pipelined grouped GEMMs (BK=32, 32 KB LDS dbuf) ===============
// LDS tile 128x32 bf16, row = 64 B. Swizzle: stored_chunk = global_chunk ^ ((row>>1)&3)
//   -> both DMA writes and ds_read_b128 are conflict-free per 8-lane phase.
// K-loop: stage(k+1 -> other buf, 4 DMA/wave) -> s_waitcnt vmcnt(4) -> barrier ->
//         16 MFMA on buf k -> barrier. Never vmcnt(0) inside the loop.

// 128x128 tile, 4 waves as 2x2 of 64x64, acc 4x4
#define GEMM_COMPUTE32(ASb, BSb)                                                \
    {                                                                           \
        bf16x8 af[4], bfr[4];                                                   \
        const int sw_ = (quad ^ ((fr >> 1) & 3)) * 8;                           \
        _Pragma("unroll")                                                       \
        for (int i_ = 0; i_ < 4; i_++)                                          \
            __builtin_memcpy(&af[i_], (ASb) + (wm + i_ * 16 + fr) * 32 + sw_, 16);\
        _Pragma("unroll")                                                       \
        for (int j_ = 0; j_ < 4; j_++)                                          \
            __builtin_memcpy(&bfr[j_], (BSb) + (wn + j_ * 16 + fr) * 32 + sw_, 16);\
        _Pragma("unroll")                                                       \
        for (int i_ = 0; i_ < 4; i_++)                                          \
            _Pragma("unroll")                                                   \
            for (int j_ = 0; j_ < 4; j_++)                                      \
                acc[i_][j_] = __builtin_amdgcn_mfma_f32_16x16x32_bf16(          \
                    af[i_], bfr[j_], acc[i_][j_], 0, 0, 0);                     \
    }

// ---------------- GEMM1: Ag @ w1bf^T -> +b1 -> gelu -> hbuf (bf16) ----------------
// grid: x = ct (XCD-affine for B stripes), y = row-block schedule
__global__ __launch_bounds__(256, 5) void k_gemm1(
    const unsigned short* __restrict__ ag, const unsigned short* __restrict__ wbf,
    const float* __restrict__ b1,
    const int* __restrict__ counts, const int* __restrict__ offs,
    const int* __restrict__ rb_e, const int* __restrict__ rb_rt,
    unsigned short* __restrict__ hbuf)
{
    const int e = rb_e[blockIdx.y];
    if (e < 0) return;
    const int rt = rb_rt[blockIdx.y], ct = blockIdx.x;
    const int ne = counts[e], off = offs[e];
    __shared__ unsigned short As[2 * 128 * 32];
    __shared__ unsigned short Bs[2 * 128 * 32];
    const int tid = threadIdx.x, wid = tid >> 6, lane = tid & 63;
    // staging lane map: row = 32*wid + 16*i_ + (lane>>2); fetch k-chunk = (lane&3)^((lane>>3)&3)
    const int srow = 32 * wid + (lane >> 2);
    const int kswz = ((lane & 3) ^ ((lane >> 3) & 3)) * 8;
    const unsigned short* gA = ag + (size_t)(off + rt * 128 + srow) * HDIM + kswz;
    const unsigned short* gB = wbf + (size_t)e * IDIM * HDIM
                             + (size_t)(ct * 128 + srow) * HDIM + kswz;
    const int wso = wid * 1024;

    f32x4 acc[4][4];
    #pragma unroll
    for (int i = 0; i < 4; i++)
        #pragma unroll
        for (int j = 0; j < 4; j++) acc[i][j] = (f32x4){0.f, 0.f, 0.f, 0.f};

    const int wm = (wid & 1) * 64, wn = (wid >> 1) * 64;
    const int fr = lane & 15, quad = lane >> 4;

    const int NK = HDIM / 32;  // 32
    {   // prologue -> buf 0
        unsigned short* dA = As + wso;
        unsigned short* dB = Bs + wso;
        gll16(gA, dA); gll16(gA + (size_t)16 * HDIM, dA + 512);
        gll16(gB, dB); gll16(gB + (size_t)16 * HDIM, dB + 512);
    }
    #pragma unroll 1
    for (int kt = 0; kt < NK - 1; ++kt) {
        const int b = kt & 1;
        unsigned short* dA = As + (1 - b) * 4096 + wso;
        unsigned short* dB = Bs + (1 - b) * 4096 + wso;
        const size_t ko = (size_t)(kt + 1) * 32;
        gll16(gA + ko, dA); gll16(gA + (size_t)16 * HDIM + ko, dA + 512);
        gll16(gB + ko, dB); gll16(gB + (size_t)16 * HDIM + ko, dB + 512);
        asm volatile("s_waitcnt vmcnt(4)" ::: "memory");
        asm volatile("s_barrier" ::: "memory");
        GEMM_COMPUTE32(As + b * 4096, Bs + b * 4096);
        asm volatile("s_barrier" ::: "memory");
    }
    asm volatile("s_waitcnt vmcnt(0)" ::: "memory");
    asm volatile("s_barrier" ::: "memory");
    GEMM_COMPUTE32(As + ((NK - 1) & 1) * 4096, Bs + ((NK - 1) & 1) * 4096);

    // epilogue: + b1, gelu(erf), -> bf16 h
    float bias[4];
    #pragma unroll
    for (int j = 0; j < 4; j++) bias[j] = b1[e * IDIM + ct * 128 + wn + j * 16 + fr];
    #pragma unroll
    for (int i = 0; i < 4; i++) {
        #pragma unroll
        for (int rg = 0; rg < 4; rg++) {
            const int r = rt * 128 + wm + i * 16 + quad * 4 + rg;
            if (r < ne) {
                unsigned short* hrow = hbuf + (size_t)(off + r) * IDIM + ct * 128 + wn + fr;
                #pragma unroll
                for (int j = 0; j < 4; j++)
                    hrow[j * 16] = f2bf(gelu_f(acc[i][j][rg] + bias[j]));
            }
        }
    }
}

// ---------------- GEMM2: hbuf @ w2bf -> +b2 -> *wt -> eo[kh][t,slot,:] ----------------
// 128x128 tile, depth-2 dbuf (r0 structure — best measured per-step efficiency).
// (a) expert==XCD clustering: bid&7 = e -> each XCD runs ONE expert; its B panel
//     and A rows are L2/L3-local (r3-verified: FETCH 309->79 MB).
// (b) split-K (big ws only): kh = slowest grid bits; 2x live blocks -> 4 blk/CU.
//     With clustered (L2-hit) loads, latency < one K-step slack, so the extra
//     waves convert to MFMA overlap (r1's split-K failed only because loads were
//     HBM-miss at 900 cyc > slack).
__global__ __launch_bounds__(256, 5) void k_gemm2(
    const unsigned short* __restrict__ hbuf, const unsigned short* __restrict__ wbf,
    const float* __restrict__ b2,
    const int* __restrict__ counts, const int* __restrict__ offs,
    const int* __restrict__ ltok, const float* __restrict__ lwt,
    float* __restrict__ eo0, float* __restrict__ eo1)
{
    const int bid = blockIdx.x;
    const int nkh = gridDim.x >> 11;          // 2048 blocks per K-segment
    const int e = bid & 7;                    // expert == XCD (bid%8 heuristic)
    const int slot = bid >> 3;
    const int ct = slot & 7;                  // 8 column tiles of N=1024
    const int r2 = slot >> 3;
    const int rt = r2 & (G2_RBG - 1);         // row-block within expert
    const int kh = r2 >> 5;                   // K-half (0 when unsplit)
    const int ne = counts[e];
    if (rt * 128 >= ne) return;
    const int off = offs[e];
    const int KSEG = (nkh == 2) ? (IDIM / 2) : IDIM;
    __shared__ unsigned short As[2 * 128 * 32];
    __shared__ unsigned short Bs[2 * 128 * 32];
    const int tid = threadIdx.x, wid = tid >> 6, lane = tid & 63;
    const int srow = 32 * wid + (lane >> 2);
    const int kswz = ((lane & 3) ^ ((lane >> 3) & 3)) * 8;
    const unsigned short* gA = hbuf + (size_t)(off + rt * 128 + srow) * IDIM
                             + kh * KSEG + kswz;
    const unsigned short* gB = wbf + (size_t)e * HDIM * IDIM
                             + (size_t)(ct * 128 + srow) * IDIM + kh * KSEG + kswz;
    const int wso = wid * 1024;

    f32x4 acc[4][4];
    #pragma unroll
    for (int i = 0; i < 4; i++)
        #pragma unroll
        for (int j = 0; j < 4; j++) acc[i][j] = (f32x4){0.f, 0.f, 0.f, 0.f};

    const int wm = (wid & 1) * 64, wn = (wid >> 1) * 64;
    const int fr = lane & 15, quad = lane >> 4;

    const int NK = KSEG / 32;  // 64 split, 128 unsplit
    {   // prologue -> buf 0
        gll16(gA, As + wso); gll16(gA + (size_t)16 * IDIM, As + wso + 512);
        gll16(gB, Bs + wso); gll16(gB + (size_t)16 * IDIM, Bs + wso + 512);
    }
    #pragma unroll 1
    for (int kt = 0; kt < NK - 1; ++kt) {
        const int b = kt & 1;
        unsigned short* dA = As + (1 - b) * 4096 + wso;
        unsigned short* dB = Bs + (1 - b) * 4096 + wso;
        const size_t ko = (size_t)(kt + 1) * 32;
        gll16(gA + ko, dA); gll16(gA + (size_t)16 * IDIM + ko, dA + 512);
        gll16(gB + ko, dB); gll16(gB + (size_t)16 * IDIM + ko, dB + 512);
        asm volatile("s_waitcnt vmcnt(4)" ::: "memory");
        asm volatile("s_barrier" ::: "memory");
        GEMM_COMPUTE32(As + b * 4096, Bs + b * 4096);
        asm volatile("s_barrier" ::: "memory");
    }
    asm volatile("s_waitcnt vmcnt(0)" ::: "memory");
    asm volatile("s_barrier" ::: "memory");
    GEMM_COMPUTE32(As + ((NK - 1) & 1) * 4096, Bs + ((NK - 1) & 1) * 4096);

    // epilogue: (+ b2 on kh==0), * routing weight, scatter fp32 partial
    float bias[4];
    #pragma unroll
    for (int j = 0; j < 4; j++)
        bias[j] = (kh == 0) ? b2[e * HDIM + ct * 128 + wn + j * 16 + fr] : 0.f;
    float* eop = (kh == 0) ? eo0 : eo1;
    #pragma unroll
    for (int i = 0; i < 4; i++) {
        #pragma unroll
        for (int rg = 0; rg < 4; rg++) {
            const int r = rt * 128 + wm + i * 16 + quad * 4 + rg;
            if (r < ne) {
                const int d = ltok[e * T_TOK + r];
                const float w = lwt[e * T_TOK + r];
                float* erow = eop + (size_t)d * HDIM + ct * 128 + wn + fr;
                #pragma unroll
                for (int j = 0; j < 4; j++)
                    erow[j * 16] = (acc[i][j][rg] + bias[j]) * w;
            }
        }
    }
}

// ---------------- combine (+ split-K partial sum) + final LN ----------------
__global__ __launch_bounds__(256) void k_final(
    const float* __restrict__ eo0, const float* __restrict__ eo1,
    const float* __restrict__ ow, const float* __restrict__ ob,
    float* __restrict__ out, int nparts)
{
    const int t = blockIdx.x, tid = threadIdx.x;
    const size_t i0 = (size_t)(t * 2 + 0) * HDIM + tid * 4;
    const size_t i1 = (size_t)(t * 2 + 1) * HDIM + tid * 4;
    float4 a = *(const float4*)(eo0 + i0);
    float4 b = *(const float4*)(eo0 + i1);
    if (nparts == 2) {
        const float4 a2 = *(const float4*)(eo1 + i0);
        const float4 b2 = *(const float4*)(eo1 + i1);
        a.x += a2.x; a.y += a2.y; a.z += a2.z; a.w += a2.w;
        b.x += b2.x; b.y += b2.y; b.z += b2.z; b.w += b2.w;
    }
    float c0 = a.x + b.x, c1 = a.y + b.y, c2 = a.z + b.z, c3 = a.w + b.w;
    float s = c0 + c1 + c2 + c3;
    float sq = c0*c0 + c1*c1 + c2*c2 + c3*c3;
    for (int o = 32; o > 0; o >>= 1) { s += __shfl_xor(s, o); sq += __shfl_xor(sq, o); }
    __shared__ float red[8];
    __shared__ float stats[2];
    const int wid = tid >> 6, lane = tid & 63;
    if (lane == 0) { red[wid] = s; red[4 + wid] = sq; }
    __syncthreads();
    if (tid == 0) {
        float S = red[0] + red[1] + red[2] + red[3];
        float Q = red[4] + red[5] + red[6] + red[7];
        float mu = S / (float)HDIM;
        float var = Q / (float)HDIM - mu * mu;
        stats[0] = mu; stats[1] = rsqrtf(var + 1e-5f);
    }
    __syncthreads();
    const float mu = stats[0], rstd = stats[1];
    const float4 w4 = *(const float4*)(ow + tid * 4);
    const float4 b4 = *(const float4*)(ob + tid * 4);
    float4 o;
    o.x = (c0 - mu) * rstd * w4.x + b4.x;
    o.y = (c1 - mu) * rstd * w4.y + b4.y;
    o.z = (c2 - mu) * rstd * w4.z + b4.z;
    o.w = (c3 - mu) * rstd * w4.w + b4.w;
    *(float4*)(out + (size_t)t * HDIM + tid * 4) = o;
}

extern "C" void kernel_launch(void* const* d_in, const int* in_sizes, int n_in,
                              void* d_out, int out_size, void* d_ws, size_t ws_size,
                              hipStream_t stream) {
    const float* x   = (const float*)d_in[0];
    const float* rlw = (const float*)d_in[1];
    const float* rlb = (const float*)d_in[2];
    const float* rw  = (const float*)d_in[3];
    const float* rb  = (const float*)d_in[4];
    const float* elw = (const float*)d_in[5];
    const float* elb = (const float*)d_in[6];
    const float* w1  = (const float*)d_in[7];
    const float* b1  = (const float*)d_in[8];
    const float* w2  = (const float*)d_in[9];
    const float* b2  = (const float*)d_in[10];
    const float* ow  = (const float*)d_in[11];
    const float* ob  = (const float*)d_in[12];
    float* out = (float*)d_out;

    const size_t MB = 1024 * 1024;
    char* ws = (char*)d_ws;
    const bool big = ws_size >= 242 * MB;
    // small (~160.3 MB): wbf1 [0,64) | hbuf/xhat [64,128) | ag+eo share [128,160) | tail
    //   (w2 converted into wbf1 AFTER gemm1; no room for split-K partials -> unsplit)
    // big (~241.3 MB):   wbf1 [0,64) | hbuf/xhat [64,128) | wbf2 [128,192) |
    //                    eo0 [192,224) | ag [224,240.3) | tail — w2 converted up-front.
    //   split-K=2: fp32 partial eo1 (32 MB) aliases wbf1 at [0,32) — wbf1 dead
    //   after gemm1 (stream-sequential kernels).
    unsigned short* wbf1 = (unsigned short*)(ws);
    unsigned short* hbuf = (unsigned short*)(ws + 64 * MB);
    unsigned short* xhat = (unsigned short*)(ws + 64 * MB);
    unsigned short* wbf2 = big ? (unsigned short*)(ws + 128 * MB) : wbf1;
    float* eo0           = big ? (float*)(ws + 192 * MB) : (float*)(ws + 128 * MB);
    float* eo1           = big ? (float*)(ws) : eo0;
    unsigned short* ag   = big ? (unsigned short*)(ws + 224 * MB)
                               : (unsigned short*)(ws + 128 * MB);
    char* tail           = ws + (big ? 241 * MB : 160 * MB);
    int* ltok            = (int*)(tail);
    float* lwt           = (float*)(tail + 131072);
    int* counts          = (int*)(tail + 262144);
    int* offs            = (int*)(tail + 262144 + 64);
    int* rb_e            = (int*)(tail + 262144 + 128);
    int* rb_rt           = (int*)(tail + 262144 + 512);

    const int ksplit = big ? 2 : 1;

    hipMemsetAsync(counts, 0, 8 * sizeof(int), stream);
    // w1 [E][H][I] -> wbf1 [E][I][H] bf16
    k_cvt_t<<<dim3(IDIM / 64, HDIM / 64, NEXP), dim3(256), 0, stream>>>(w1, wbf1, HDIM, IDIM);
    if (big)  // w2 [E][I][H] -> wbf2 [E][H][I] bf16, up-front (keeps hbuf L3-hot later)
        k_cvt_t<<<dim3(HDIM / 64, IDIM / 64, NEXP), dim3(256), 0, stream>>>(w2, wbf2, IDIM, HDIM);
    k_ln_router<<<dim3(T_TOK), dim3(256), 0, stream>>>(x, rlw, rlb, rw, rb, xhat, counts, ltok, lwt);
    k_sched<<<dim3(1), dim3(64), 0, stream>>>(counts, offs, rb_e, rb_rt);
    k_ag_build<<<dim3(32, 4, NEXP), dim3(256), 0, stream>>>(xhat, elw, elb, counts, offs, ltok, ag);
    // gemm1 grid: x = ct (XCD-affine), y = compacted row-block schedule
    k_gemm1<<<dim3(IDIM / 128, MAXRB), dim3(256), 0, stream>>>(
        ag, wbf1, b1, counts, offs, rb_e, rb_rt, hbuf);
    if (!big)
        k_cvt_t<<<dim3(HDIM / 64, IDIM / 64, NEXP), dim3(256), 0, stream>>>(w2, wbf2, IDIM, HDIM);
    // gemm2: 1D grid, expert==XCD clustering; 8 e x 8 ct x G2_RBG rt x ksplit kh
    k_gemm2<<<dim3(8 * 8 * G2_RBG * ksplit), dim3(256), 0, stream>>>(
        hbuf, wbf2, b2, counts, offs, ltok, lwt, eo0, eo1);
    k_final<<<dim3(T_TOK), dim3(256), 0, stream>>>(eo0, eo1, ow, ob, out, ksplit);
}